// Round 13
// baseline (74.432 us; speedup 1.0000x reference)
//
#include <hip/hip_runtime.h>

#define D 128
#define BM 64        // rows per gemm block
#define NBB 256      // binning blocks (subset of gemm grid)
#define BINSH 6      // 64 rows per bin
#define MAXBINS 1024
#define CAPB 1536    // entries per bin segment (avg 1023, +16 sigma)

typedef __attribute__((ext_vector_type(8))) short bf16x8;
typedef __attribute__((ext_vector_type(4))) float f32x4;

__device__ __forceinline__ unsigned short f2bf(float f) {
    unsigned u = __float_as_uint(f);
    u = (u + 0x7FFFu + ((u >> 16) & 1u)) >> 16;   // RNE
    return (unsigned short)u;
}
__device__ __forceinline__ float bf2f(unsigned short h) {
    return __uint_as_float(((unsigned)h) << 16);
}

// ---------------- prep: Wt[n][k] = bf16(W[k][n]) + zero bin counters ----------------
__global__ __launch_bounds__(128) void k_prepw(const float* __restrict__ W,
                                               unsigned short* __restrict__ Wt,
                                               int* __restrict__ gcnt, int nbins) {
    int nn = blockIdx.x, k = threadIdx.x;
    Wt[nn * D + k] = f2bf(W[k * D + nn]);
    int gtid = blockIdx.x * 128 + threadIdx.x;
    for (int i = gtid; i < nbins * 16; i += 128 * D) gcnt[i] = 0;
}

// ---------------- fused GEMM + edge binning ----------------
// K-split staging: sA 64x64 (8KB) + sB 128x64 (16KB) = 24KB -> 6 blocks/CU.
// MFMA operands SWAPPED (D = Wcol x Hrow): lane holds 4 consecutive W-cols of
// one H-row per ct-tile -> epilogue = 8 coalesced-granule 8B stores (was 32x2B).
__global__ __launch_bounds__(256) void k_gemm_bin(const float* __restrict__ H,
                                                  const unsigned short* __restrict__ Wt,
                                                  unsigned short* __restrict__ HWb,
                                                  int n,
                                                  const int* __restrict__ rows,
                                                  const int* __restrict__ cols,
                                                  const float* __restrict__ vals,
                                                  int* __restrict__ gcnt,
                                                  int2* __restrict__ segs,
                                                  int E, int nbins, int nbb) {
    __shared__ unsigned short sA[BM * 64];    // 8KB  (bin phase reuses as lcnt/loff)
    __shared__ unsigned short sB[D * 64];     // 16KB
    const int tid = threadIdx.x;
    const int row0 = blockIdx.x * BM;
    const int w = tid >> 6, l = tid & 63;
    const int lr = l & 15, lq = l >> 4;

    f32x4 acc[8];
#pragma unroll
    for (int ct = 0; ct < 8; ++ct) acc[ct] = (f32x4){0.f, 0.f, 0.f, 0.f};

#pragma unroll
    for (int kt = 0; kt < 2; ++kt) {
        if (kt) __syncthreads();
        // stage sB half: Wt[*][kt*64..+63] -> 1024 chunks of bf16x8, 4/thread
#pragma unroll
        for (int s = 0; s < 4; ++s) {
            int idx = s * 256 + tid;
            int r = idx >> 3, cc = idx & 7;
            bf16x8 v = *reinterpret_cast<const bf16x8*>(&Wt[(size_t)r * D + kt * 64 + cc * 8]);
            *reinterpret_cast<bf16x8*>(&sB[r * 64 + ((cc ^ (r & 7)) * 8)]) = v;
        }
        // stage sA half: H[row0..+63][kt*64..+63] fp32->bf16, 512 chunks, 2/thread
#pragma unroll
        for (int s = 0; s < 2; ++s) {
            int idx = s * 256 + tid;
            int r = idx >> 3, cc = idx & 7;
            int row = row0 + r;
            float4 u0 = make_float4(0.f, 0.f, 0.f, 0.f), u1 = u0;
            if (row < n) {
                const float4* p = reinterpret_cast<const float4*>(
                    &H[(size_t)row * D + kt * 64 + cc * 8]);
                u0 = p[0]; u1 = p[1];
            }
            bf16x8 v;
            v[0] = (short)f2bf(u0.x); v[1] = (short)f2bf(u0.y);
            v[2] = (short)f2bf(u0.z); v[3] = (short)f2bf(u0.w);
            v[4] = (short)f2bf(u1.x); v[5] = (short)f2bf(u1.y);
            v[6] = (short)f2bf(u1.z); v[7] = (short)f2bf(u1.w);
            *reinterpret_cast<bf16x8*>(&sA[r * 64 + ((cc ^ (r & 7)) * 8)]) = v;
        }
        __syncthreads();

#pragma unroll
        for (int ks = 0; ks < 2; ++ks) {
            const int arow = w * 16 + lr;
            const int acc_c = (ks * 4 + lq) ^ (arow & 7);
            bf16x8 a = *reinterpret_cast<const bf16x8*>(&sA[arow * 64 + acc_c * 8]);
#pragma unroll
            for (int ct = 0; ct < 8; ++ct) {
                const int brow = ct * 16 + lr;
                const int bcc = (ks * 4 + lq) ^ (brow & 7);
                bf16x8 b = *reinterpret_cast<const bf16x8*>(&sB[brow * 64 + bcc * 8]);
                // swapped operands: D[m=wcol][n=hrow]
                acc[ct] = __builtin_amdgcn_mfma_f32_16x16x32_bf16(b, a, acc[ct], 0, 0, 0);
            }
        }
    }

    // epilogue: lane holds HW[row0+w*16+lr][ct*16+lq*4 .. +3] -> 8B stores
    {
        int row = row0 + w * 16 + lr;
        if (row < n) {
#pragma unroll
            for (int ct = 0; ct < 8; ++ct) {
                ushort4 o;
                o.x = f2bf(acc[ct][0]); o.y = f2bf(acc[ct][1]);
                o.z = f2bf(acc[ct][2]); o.w = f2bf(acc[ct][3]);
                *reinterpret_cast<ushort4*>(&HWb[(size_t)row * D + ct * 16 + lq * 4]) = o;
            }
        }
    }

    // ---------------- bin phase (first nbb blocks only) ----------------
    if (blockIdx.x < (unsigned)nbb) {
        __syncthreads();                       // all waves done with sA
        int* lcnt = reinterpret_cast<int*>(sA);          // 4KB of 8KB
        int* loff = lcnt + MAXBINS;                      // next 4KB
        int chunk = (E + nbb - 1) / nbb;
        int s = blockIdx.x * chunk;
        int epos = s + chunk; if (epos > E) epos = E;
        for (int i = tid; i < nbins; i += 256) lcnt[i] = 0;
        __syncthreads();
        for (int e = s + tid; e < epos; e += 256)
            atomicAdd(&lcnt[rows[e] >> BINSH], 1);       // HW ds_add
        __syncthreads();
        for (int i = tid; i < nbins; i += 256) {
            int c = lcnt[i];
            int base = c ? atomicAdd(&gcnt[i * 16], c) : 0;
            loff[i] = i * CAPB + base;
            lcnt[i] = 0;                                 // reuse as cursor
        }
        __syncthreads();
        for (int e = s + tid; e < epos; e += 256) {
            int r = rows[e];
            int c = cols[e];
            float v = vals[e];
            int bin = r >> BINSH;
            int p = atomicAdd(&lcnt[bin], 1);
            int pos = loff[bin] + p;
            if (pos < (bin + 1) * CAPB)                  // overflow guard
                segs[pos] = make_int2(((r & 63) << 16) | c, __float_as_int(v));
        }
    }
}

// ---------------- pass 2: per-bin row-sort in LDS + register-accum gather ----------------
__global__ __launch_bounds__(512) void k_spmm(const unsigned short* __restrict__ HWb,
                                              const int* __restrict__ gcnt,
                                              const int2* __restrict__ segs,
                                              const float* __restrict__ bias,
                                              float* __restrict__ out, int n) {
    __shared__ int2 sent[CAPB];     // 12KB
    __shared__ int lcnt[64];
    __shared__ int loff[64];
    __shared__ int lcur[64];
    const int b = blockIdx.x;
    int cnt = gcnt[b * 16];
    if (cnt > CAPB) cnt = CAPB;
    const int2* seg = segs + (size_t)b * CAPB;

    if (threadIdx.x < 64) lcnt[threadIdx.x] = 0;
    __syncthreads();
    int2 er[3];
#pragma unroll
    for (int k = 0; k < 3; ++k) {
        int i = threadIdx.x + k * 512;
        if (i < cnt) {
            er[k] = seg[i];
            atomicAdd(&lcnt[((unsigned)er[k].x) >> 16], 1);
        }
    }
    __syncthreads();
    if (threadIdx.x < 64) {
        int v = lcnt[threadIdx.x];
        int inc = v;
#pragma unroll
        for (int o = 1; o < 64; o <<= 1) {
            int t = __shfl_up(inc, o);
            if (threadIdx.x >= o) inc += t;
        }
        loff[threadIdx.x] = inc - v;
        lcur[threadIdx.x] = inc - v;
    }
    __syncthreads();
#pragma unroll
    for (int k = 0; k < 3; ++k) {
        int i = threadIdx.x + k * 512;
        if (i < cnt) {
            int p = atomicAdd(&lcur[((unsigned)er[k].x) >> 16], 1);
            sent[p] = er[k];
        }
    }
    __syncthreads();

    const int w = threadIdx.x >> 6, lane = threadIdx.x & 63;
    const unsigned c2 = 2 * lane;
    const float2 bb = *reinterpret_cast<const float2*>(&bias[c2]);

    for (int rr = w; rr < 64; rr += 8) {
        int row = b * 64 + rr;
        if (row >= n) break;
        int s = loff[rr];
        int deg = lcnt[rr];
        float a0 = 0.f, a1 = 0.f, b0 = 0.f, b1 = 0.f;
        int t = 0;
        for (; t + 8 <= deg; t += 8) {
            int2 e0 = sent[s + t],     e1 = sent[s + t + 1];
            int2 e2 = sent[s + t + 2], e3 = sent[s + t + 3];
            int2 e4 = sent[s + t + 4], e5 = sent[s + t + 5];
            int2 e6 = sent[s + t + 6], e7 = sent[s + t + 7];
            unsigned m0 = *reinterpret_cast<const unsigned*>(&HWb[(size_t)(e0.x & 0xFFFF) * D + c2]);
            unsigned m1 = *reinterpret_cast<const unsigned*>(&HWb[(size_t)(e1.x & 0xFFFF) * D + c2]);
            unsigned m2 = *reinterpret_cast<const unsigned*>(&HWb[(size_t)(e2.x & 0xFFFF) * D + c2]);
            unsigned m3 = *reinterpret_cast<const unsigned*>(&HWb[(size_t)(e3.x & 0xFFFF) * D + c2]);
            unsigned m4 = *reinterpret_cast<const unsigned*>(&HWb[(size_t)(e4.x & 0xFFFF) * D + c2]);
            unsigned m5 = *reinterpret_cast<const unsigned*>(&HWb[(size_t)(e5.x & 0xFFFF) * D + c2]);
            unsigned m6 = *reinterpret_cast<const unsigned*>(&HWb[(size_t)(e6.x & 0xFFFF) * D + c2]);
            unsigned m7 = *reinterpret_cast<const unsigned*>(&HWb[(size_t)(e7.x & 0xFFFF) * D + c2]);
            float v0 = __int_as_float(e0.y), v1 = __int_as_float(e1.y);
            float v2 = __int_as_float(e2.y), v3 = __int_as_float(e3.y);
            float v4 = __int_as_float(e4.y), v5 = __int_as_float(e5.y);
            float v6 = __int_as_float(e6.y), v7 = __int_as_float(e7.y);
            a0 += v0 * bf2f((unsigned short)(m0 & 0xFFFF));
            a1 += v0 * bf2f((unsigned short)(m0 >> 16));
            b0 += v1 * bf2f((unsigned short)(m1 & 0xFFFF));
            b1 += v1 * bf2f((unsigned short)(m1 >> 16));
            a0 += v2 * bf2f((unsigned short)(m2 & 0xFFFF));
            a1 += v2 * bf2f((unsigned short)(m2 >> 16));
            b0 += v3 * bf2f((unsigned short)(m3 & 0xFFFF));
            b1 += v3 * bf2f((unsigned short)(m3 >> 16));
            a0 += v4 * bf2f((unsigned short)(m4 & 0xFFFF));
            a1 += v4 * bf2f((unsigned short)(m4 >> 16));
            b0 += v5 * bf2f((unsigned short)(m5 & 0xFFFF));
            b1 += v5 * bf2f((unsigned short)(m5 >> 16));
            a0 += v6 * bf2f((unsigned short)(m6 & 0xFFFF));
            a1 += v6 * bf2f((unsigned short)(m6 >> 16));
            b0 += v7 * bf2f((unsigned short)(m7 & 0xFFFF));
            b1 += v7 * bf2f((unsigned short)(m7 >> 16));
        }
        for (; t < deg; ++t) {
            int2 e = sent[s + t];
            unsigned m = *reinterpret_cast<const unsigned*>(&HWb[(size_t)(e.x & 0xFFFF) * D + c2]);
            float v = __int_as_float(e.y);
            a0 += v * bf2f((unsigned short)(m & 0xFFFF));
            a1 += v * bf2f((unsigned short)(m >> 16));
        }
        float2 o;
        o.x = fmaxf(a0 + b0 + bb.x, 0.f);
        o.y = fmaxf(a1 + b1 + bb.y, 0.f);
        *reinterpret_cast<float2*>(&out[(size_t)row * D + c2]) = o;
    }
}

// ---------------- Fallback path (small ws): atomic scatter ----------------
__global__ void k_init_bias(const float* __restrict__ bias, float* __restrict__ out, int n) {
    int i = blockIdx.x * blockDim.x + threadIdx.x;
    if (i < n * D) out[i] = bias[i & (D - 1)];
}
__global__ void k_scatter(const unsigned short* __restrict__ HWb, const int* __restrict__ rows,
                          const int* __restrict__ cols, const float* __restrict__ vals,
                          float* __restrict__ out, int E) {
    int e = blockIdx.x * 2 + (threadIdx.x >> 7);
    int j = threadIdx.x & (D - 1);
    if (e < E) {
        int r = rows[e];
        int c = cols[e];
        float v = vals[e];
        atomicAdd(&out[(size_t)r * D + j], v * bf2f(HWb[(size_t)c * D + j]));
    }
}
__global__ void k_relu(float* __restrict__ out, int n) {
    int i = blockIdx.x * blockDim.x + threadIdx.x;
    if (i < n * D) out[i] = fmaxf(out[i], 0.f);
}

extern "C" void kernel_launch(void* const* d_in, const int* in_sizes, int n_in,
                              void* d_out, int out_size, void* d_ws, size_t ws_size,
                              hipStream_t stream) {
    const float* H         = (const float*)d_in[0];
    const float* W         = (const float*)d_in[1];
    const float* bias      = (const float*)d_in[2];
    const float* edge_vals = (const float*)d_in[3];
    const int*   edge_rows = (const int*)d_in[4];
    const int*   edge_cols = (const int*)d_in[5];
    float* out = (float*)d_out;

    const int n = in_sizes[0] / D;   // 50000
    const int E = in_sizes[3];       // 800000
    const int gblocks = (n + BM - 1) / BM;
    const int nbins = (n + 63) >> BINSH;   // 782
    const int nbb = (gblocks < NBB) ? gblocks : NBB;

    char* ws = (char*)d_ws;
    unsigned short* HWb = (unsigned short*)ws; ws += (size_t)n * D * sizeof(unsigned short);
    unsigned short* Wt  = (unsigned short*)ws; ws += (size_t)D * D * sizeof(unsigned short);
    int* gcnt = (int*)ws;            ws += (size_t)nbins * 16 * sizeof(int);
    int2* segs = (int2*)ws;          ws += (size_t)nbins * CAPB * sizeof(int2);
    size_t need_full = (size_t)(ws - (char*)d_ws);

    k_prepw<<<D, D, 0, stream>>>(W, Wt, gcnt, nbins);

    if (ws_size >= need_full && n < 65536 && nbins <= MAXBINS) {
        k_gemm_bin<<<gblocks, 256, 0, stream>>>(H, Wt, HWb, n,
                                                edge_rows, edge_cols, edge_vals,
                                                gcnt, segs, E, nbins, nbb);
        k_spmm<<<nbins, 512, 0, stream>>>(HWb, gcnt, segs, bias, out, n);
    } else {
        k_gemm_bin<<<gblocks, 256, 0, stream>>>(H, Wt, HWb, n,
                                                edge_rows, edge_cols, edge_vals,
                                                (int*)d_ws, (int2*)d_ws, 0, nbins, 0);
        k_init_bias<<<((size_t)n * D + 255) / 256, 256, 0, stream>>>(bias, out, n);
        k_scatter<<<(E + 1) / 2, 256, 0, stream>>>(HWb, edge_rows, edge_cols, edge_vals, out, E);
        k_relu<<<((size_t)n * D + 255) / 256, 256, 0, stream>>>(out, n);
    }
}

// Round 14
// 69.259 us; speedup vs baseline: 1.0747x; 1.0747x over previous
//
#include <hip/hip_runtime.h>

#define D 128
#define BM 64        // rows per gemm block
#define NBB 256      // binning blocks (subset of gemm grid)
#define BINSH 6      // 64 rows per bin
#define MAXBINS 1024
#define CAPB 1536    // entries per bin segment (avg 1023, +16 sigma)

typedef __attribute__((ext_vector_type(8))) short bf16x8;
typedef __attribute__((ext_vector_type(4))) float f32x4;

__device__ __forceinline__ unsigned short f2bf(float f) {
    unsigned u = __float_as_uint(f);
    u = (u + 0x7FFFu + ((u >> 16) & 1u)) >> 16;   // RNE
    return (unsigned short)u;
}
__device__ __forceinline__ float bf2f(unsigned short h) {
    return __uint_as_float(((unsigned)h) << 16);
}

// ---------------- prep: Wt[n][k] = bf16(W[k][n]) + zero bin counters ----------------
__global__ __launch_bounds__(128) void k_prepw(const float* __restrict__ W,
                                               unsigned short* __restrict__ Wt,
                                               int* __restrict__ gcnt, int nbins) {
    int nn = blockIdx.x, k = threadIdx.x;
    Wt[nn * D + k] = f2bf(W[k * D + nn]);
    int gtid = blockIdx.x * 128 + threadIdx.x;
    for (int i = gtid; i < nbins * 16; i += 128 * D) gcnt[i] = 0;
}

// ---------------- fused GEMM + edge binning ----------------
// gemm: K-split staging (24KB LDS), swapped MFMA operands, 8B epilogue stores.
// bin (blocks 0..nbb-1, after gemm): 4x-unrolled int4/float4 edge processing —
// 4 independent LDS-atomic->store chains per thread hide the tail latency.
__global__ __launch_bounds__(256) void k_gemm_bin(const float* __restrict__ H,
                                                  const unsigned short* __restrict__ Wt,
                                                  unsigned short* __restrict__ HWb,
                                                  int n,
                                                  const int* __restrict__ rows,
                                                  const int* __restrict__ cols,
                                                  const float* __restrict__ vals,
                                                  int* __restrict__ gcnt,
                                                  int2* __restrict__ segs,
                                                  int E, int nbins, int nbb) {
    __shared__ unsigned short sA[BM * 64];    // 8KB  (bin phase reuses as lcnt/loff)
    __shared__ unsigned short sB[D * 64];     // 16KB
    const int tid = threadIdx.x;
    const int row0 = blockIdx.x * BM;
    const int w = tid >> 6, l = tid & 63;
    const int lr = l & 15, lq = l >> 4;

    f32x4 acc[8];
#pragma unroll
    for (int ct = 0; ct < 8; ++ct) acc[ct] = (f32x4){0.f, 0.f, 0.f, 0.f};

#pragma unroll
    for (int kt = 0; kt < 2; ++kt) {
        if (kt) __syncthreads();
#pragma unroll
        for (int s = 0; s < 4; ++s) {
            int idx = s * 256 + tid;
            int r = idx >> 3, cc = idx & 7;
            bf16x8 v = *reinterpret_cast<const bf16x8*>(&Wt[(size_t)r * D + kt * 64 + cc * 8]);
            *reinterpret_cast<bf16x8*>(&sB[r * 64 + ((cc ^ (r & 7)) * 8)]) = v;
        }
#pragma unroll
        for (int s = 0; s < 2; ++s) {
            int idx = s * 256 + tid;
            int r = idx >> 3, cc = idx & 7;
            int row = row0 + r;
            float4 u0 = make_float4(0.f, 0.f, 0.f, 0.f), u1 = u0;
            if (row < n) {
                const float4* p = reinterpret_cast<const float4*>(
                    &H[(size_t)row * D + kt * 64 + cc * 8]);
                u0 = p[0]; u1 = p[1];
            }
            bf16x8 v;
            v[0] = (short)f2bf(u0.x); v[1] = (short)f2bf(u0.y);
            v[2] = (short)f2bf(u0.z); v[3] = (short)f2bf(u0.w);
            v[4] = (short)f2bf(u1.x); v[5] = (short)f2bf(u1.y);
            v[6] = (short)f2bf(u1.z); v[7] = (short)f2bf(u1.w);
            *reinterpret_cast<bf16x8*>(&sA[r * 64 + ((cc ^ (r & 7)) * 8)]) = v;
        }
        __syncthreads();

#pragma unroll
        for (int ks = 0; ks < 2; ++ks) {
            const int arow = w * 16 + lr;
            const int acc_c = (ks * 4 + lq) ^ (arow & 7);
            bf16x8 a = *reinterpret_cast<const bf16x8*>(&sA[arow * 64 + acc_c * 8]);
#pragma unroll
            for (int ct = 0; ct < 8; ++ct) {
                const int brow = ct * 16 + lr;
                const int bcc = (ks * 4 + lq) ^ (brow & 7);
                bf16x8 b = *reinterpret_cast<const bf16x8*>(&sB[brow * 64 + bcc * 8]);
                acc[ct] = __builtin_amdgcn_mfma_f32_16x16x32_bf16(b, a, acc[ct], 0, 0, 0);
            }
        }
    }

    {
        int row = row0 + w * 16 + lr;
        if (row < n) {
#pragma unroll
            for (int ct = 0; ct < 8; ++ct) {
                ushort4 o;
                o.x = f2bf(acc[ct][0]); o.y = f2bf(acc[ct][1]);
                o.z = f2bf(acc[ct][2]); o.w = f2bf(acc[ct][3]);
                *reinterpret_cast<ushort4*>(&HWb[(size_t)row * D + ct * 16 + lq * 4]) = o;
            }
        }
    }

    // ---------------- bin phase (first nbb blocks, 4x unrolled) ----------------
    if (blockIdx.x < (unsigned)nbb) {
        __syncthreads();                       // all waves done with sA
        int* lcnt = reinterpret_cast<int*>(sA);          // 4KB of 8KB
        int* loff = lcnt + MAXBINS;                      // next 4KB
        int chunk = (E + nbb - 1) / nbb;
        chunk = (chunk + 3) & ~3;                        // 16B-aligned chunk start
        int s = blockIdx.x * chunk;
        int epos = s + chunk; if (epos > E) epos = E;
        for (int i = tid; i < nbins; i += 256) lcnt[i] = 0;
        __syncthreads();
        if (s < E) {
            const int t0 = s + ((epos - s) & ~3);
            for (int base = s + tid * 4; base + 4 <= epos; base += 1024) {
                int4 r4 = *reinterpret_cast<const int4*>(&rows[base]);
                atomicAdd(&lcnt[r4.x >> BINSH], 1);
                atomicAdd(&lcnt[r4.y >> BINSH], 1);
                atomicAdd(&lcnt[r4.z >> BINSH], 1);
                atomicAdd(&lcnt[r4.w >> BINSH], 1);
            }
            for (int e = t0 + tid; e < epos; e += 256)
                atomicAdd(&lcnt[rows[e] >> BINSH], 1);
        }
        __syncthreads();
        for (int i = tid; i < nbins; i += 256) {
            int c = lcnt[i];
            int base = c ? atomicAdd(&gcnt[i * 16], c) : 0;
            loff[i] = i * CAPB + base;
            lcnt[i] = 0;                                 // reuse as cursor
        }
        __syncthreads();
        if (s < E) {
            const int t0 = s + ((epos - s) & ~3);
            for (int base = s + tid * 4; base + 4 <= epos; base += 1024) {
                int4 r4 = *reinterpret_cast<const int4*>(&rows[base]);
                int4 c4 = *reinterpret_cast<const int4*>(&cols[base]);
                float4 v4 = *reinterpret_cast<const float4*>(&vals[base]);
                int bn0 = r4.x >> BINSH, bn1 = r4.y >> BINSH;
                int bn2 = r4.z >> BINSH, bn3 = r4.w >> BINSH;
                int p0 = atomicAdd(&lcnt[bn0], 1);
                int p1 = atomicAdd(&lcnt[bn1], 1);
                int p2 = atomicAdd(&lcnt[bn2], 1);
                int p3 = atomicAdd(&lcnt[bn3], 1);
                int q0 = loff[bn0] + p0, q1 = loff[bn1] + p1;
                int q2 = loff[bn2] + p2, q3 = loff[bn3] + p3;
                if (q0 < (bn0 + 1) * CAPB)
                    segs[q0] = make_int2(((r4.x & 63) << 16) | c4.x, __float_as_int(v4.x));
                if (q1 < (bn1 + 1) * CAPB)
                    segs[q1] = make_int2(((r4.y & 63) << 16) | c4.y, __float_as_int(v4.y));
                if (q2 < (bn2 + 1) * CAPB)
                    segs[q2] = make_int2(((r4.z & 63) << 16) | c4.z, __float_as_int(v4.z));
                if (q3 < (bn3 + 1) * CAPB)
                    segs[q3] = make_int2(((r4.w & 63) << 16) | c4.w, __float_as_int(v4.w));
            }
            for (int e = t0 + tid; e < epos; e += 256) {
                int r = rows[e];
                int bin = r >> BINSH;
                int p = atomicAdd(&lcnt[bin], 1);
                int pos = loff[bin] + p;
                if (pos < (bin + 1) * CAPB)
                    segs[pos] = make_int2(((r & 63) << 16) | cols[e], __float_as_int(vals[e]));
            }
        }
    }
}

// ---------------- pass 2: per-bin row-sort in LDS + register-accum gather ----------------
__global__ __launch_bounds__(512) void k_spmm(const unsigned short* __restrict__ HWb,
                                              const int* __restrict__ gcnt,
                                              const int2* __restrict__ segs,
                                              const float* __restrict__ bias,
                                              float* __restrict__ out, int n) {
    __shared__ int2 sent[CAPB];     // 12KB
    __shared__ int lcnt[64];
    __shared__ int loff[64];
    __shared__ int lcur[64];
    const int b = blockIdx.x;
    int cnt = gcnt[b * 16];
    if (cnt > CAPB) cnt = CAPB;
    const int2* seg = segs + (size_t)b * CAPB;

    if (threadIdx.x < 64) lcnt[threadIdx.x] = 0;
    __syncthreads();
    int2 er[3];
#pragma unroll
    for (int k = 0; k < 3; ++k) {
        int i = threadIdx.x + k * 512;
        if (i < cnt) {
            er[k] = seg[i];
            atomicAdd(&lcnt[((unsigned)er[k].x) >> 16], 1);
        }
    }
    __syncthreads();
    if (threadIdx.x < 64) {
        int v = lcnt[threadIdx.x];
        int inc = v;
#pragma unroll
        for (int o = 1; o < 64; o <<= 1) {
            int t = __shfl_up(inc, o);
            if (threadIdx.x >= o) inc += t;
        }
        loff[threadIdx.x] = inc - v;
        lcur[threadIdx.x] = inc - v;
    }
    __syncthreads();
#pragma unroll
    for (int k = 0; k < 3; ++k) {
        int i = threadIdx.x + k * 512;
        if (i < cnt) {
            int p = atomicAdd(&lcur[((unsigned)er[k].x) >> 16], 1);
            sent[p] = er[k];
        }
    }
    __syncthreads();

    const int w = threadIdx.x >> 6, lane = threadIdx.x & 63;
    const unsigned c2 = 2 * lane;
    const float2 bb = *reinterpret_cast<const float2*>(&bias[c2]);

    for (int rr = w; rr < 64; rr += 8) {
        int row = b * 64 + rr;
        if (row >= n) break;
        int s = loff[rr];
        int deg = lcnt[rr];
        float a0 = 0.f, a1 = 0.f, b0 = 0.f, b1 = 0.f;
        int t = 0;
        for (; t + 8 <= deg; t += 8) {
            int2 e0 = sent[s + t],     e1 = sent[s + t + 1];
            int2 e2 = sent[s + t + 2], e3 = sent[s + t + 3];
            int2 e4 = sent[s + t + 4], e5 = sent[s + t + 5];
            int2 e6 = sent[s + t + 6], e7 = sent[s + t + 7];
            unsigned m0 = *reinterpret_cast<const unsigned*>(&HWb[(size_t)(e0.x & 0xFFFF) * D + c2]);
            unsigned m1 = *reinterpret_cast<const unsigned*>(&HWb[(size_t)(e1.x & 0xFFFF) * D + c2]);
            unsigned m2 = *reinterpret_cast<const unsigned*>(&HWb[(size_t)(e2.x & 0xFFFF) * D + c2]);
            unsigned m3 = *reinterpret_cast<const unsigned*>(&HWb[(size_t)(e3.x & 0xFFFF) * D + c2]);
            unsigned m4 = *reinterpret_cast<const unsigned*>(&HWb[(size_t)(e4.x & 0xFFFF) * D + c2]);
            unsigned m5 = *reinterpret_cast<const unsigned*>(&HWb[(size_t)(e5.x & 0xFFFF) * D + c2]);
            unsigned m6 = *reinterpret_cast<const unsigned*>(&HWb[(size_t)(e6.x & 0xFFFF) * D + c2]);
            unsigned m7 = *reinterpret_cast<const unsigned*>(&HWb[(size_t)(e7.x & 0xFFFF) * D + c2]);
            float v0 = __int_as_float(e0.y), v1 = __int_as_float(e1.y);
            float v2 = __int_as_float(e2.y), v3 = __int_as_float(e3.y);
            float v4 = __int_as_float(e4.y), v5 = __int_as_float(e5.y);
            float v6 = __int_as_float(e6.y), v7 = __int_as_float(e7.y);
            a0 += v0 * bf2f((unsigned short)(m0 & 0xFFFF));
            a1 += v0 * bf2f((unsigned short)(m0 >> 16));
            b0 += v1 * bf2f((unsigned short)(m1 & 0xFFFF));
            b1 += v1 * bf2f((unsigned short)(m1 >> 16));
            a0 += v2 * bf2f((unsigned short)(m2 & 0xFFFF));
            a1 += v2 * bf2f((unsigned short)(m2 >> 16));
            b0 += v3 * bf2f((unsigned short)(m3 & 0xFFFF));
            b1 += v3 * bf2f((unsigned short)(m3 >> 16));
            a0 += v4 * bf2f((unsigned short)(m4 & 0xFFFF));
            a1 += v4 * bf2f((unsigned short)(m4 >> 16));
            b0 += v5 * bf2f((unsigned short)(m5 & 0xFFFF));
            b1 += v5 * bf2f((unsigned short)(m5 >> 16));
            a0 += v6 * bf2f((unsigned short)(m6 & 0xFFFF));
            a1 += v6 * bf2f((unsigned short)(m6 >> 16));
            b0 += v7 * bf2f((unsigned short)(m7 & 0xFFFF));
            b1 += v7 * bf2f((unsigned short)(m7 >> 16));
        }
        for (; t < deg; ++t) {
            int2 e = sent[s + t];
            unsigned m = *reinterpret_cast<const unsigned*>(&HWb[(size_t)(e.x & 0xFFFF) * D + c2]);
            float v = __int_as_float(e.y);
            a0 += v * bf2f((unsigned short)(m & 0xFFFF));
            a1 += v * bf2f((unsigned short)(m >> 16));
        }
        float2 o;
        o.x = fmaxf(a0 + b0 + bb.x, 0.f);
        o.y = fmaxf(a1 + b1 + bb.y, 0.f);
        *reinterpret_cast<float2*>(&out[(size_t)row * D + c2]) = o;
    }
}

// ---------------- Fallback path (small ws): atomic scatter ----------------
__global__ void k_init_bias(const float* __restrict__ bias, float* __restrict__ out, int n) {
    int i = blockIdx.x * blockDim.x + threadIdx.x;
    if (i < n * D) out[i] = bias[i & (D - 1)];
}
__global__ void k_scatter(const unsigned short* __restrict__ HWb, const int* __restrict__ rows,
                          const int* __restrict__ cols, const float* __restrict__ vals,
                          float* __restrict__ out, int E) {
    int e = blockIdx.x * 2 + (threadIdx.x >> 7);
    int j = threadIdx.x & (D - 1);
    if (e < E) {
        int r = rows[e];
        int c = cols[e];
        float v = vals[e];
        atomicAdd(&out[(size_t)r * D + j], v * bf2f(HWb[(size_t)c * D + j]));
    }
}
__global__ void k_relu(float* __restrict__ out, int n) {
    int i = blockIdx.x * blockDim.x + threadIdx.x;
    if (i < n * D) out[i] = fmaxf(out[i], 0.f);
}

extern "C" void kernel_launch(void* const* d_in, const int* in_sizes, int n_in,
                              void* d_out, int out_size, void* d_ws, size_t ws_size,
                              hipStream_t stream) {
    const float* H         = (const float*)d_in[0];
    const float* W         = (const float*)d_in[1];
    const float* bias      = (const float*)d_in[2];
    const float* edge_vals = (const float*)d_in[3];
    const int*   edge_rows = (const int*)d_in[4];
    const int*   edge_cols = (const int*)d_in[5];
    float* out = (float*)d_out;

    const int n = in_sizes[0] / D;   // 50000
    const int E = in_sizes[3];       // 800000
    const int gblocks = (n + BM - 1) / BM;
    const int nbins = (n + 63) >> BINSH;   // 782
    const int nbb = (gblocks < NBB) ? gblocks : NBB;

    char* ws = (char*)d_ws;
    unsigned short* HWb = (unsigned short*)ws; ws += (size_t)n * D * sizeof(unsigned short);
    unsigned short* Wt  = (unsigned short*)ws; ws += (size_t)D * D * sizeof(unsigned short);
    int* gcnt = (int*)ws;            ws += (size_t)nbins * 16 * sizeof(int);
    int2* segs = (int2*)ws;          ws += (size_t)nbins * CAPB * sizeof(int2);
    size_t need_full = (size_t)(ws - (char*)d_ws);

    k_prepw<<<D, D, 0, stream>>>(W, Wt, gcnt, nbins);

    if (ws_size >= need_full && n < 65536 && nbins <= MAXBINS) {
        k_gemm_bin<<<gblocks, 256, 0, stream>>>(H, Wt, HWb, n,
                                                edge_rows, edge_cols, edge_vals,
                                                gcnt, segs, E, nbins, nbb);
        k_spmm<<<nbins, 512, 0, stream>>>(HWb, gcnt, segs, bias, out, n);
    } else {
        k_gemm_bin<<<gblocks, 256, 0, stream>>>(H, Wt, HWb, n,
                                                edge_rows, edge_cols, edge_vals,
                                                (int*)d_ws, (int2*)d_ws, 0, nbins, 0);
        k_init_bias<<<((size_t)n * D + 255) / 256, 256, 0, stream>>>(bias, out, n);
        k_scatter<<<(E + 1) / 2, 256, 0, stream>>>(HWb, edge_rows, edge_cols, edge_vals, out, E);
        k_relu<<<((size_t)n * D + 255) / 256, 256, 0, stream>>>(out, n);
    }
}